// Round 1
// baseline (1672.056 us; speedup 1.0000x reference)
//
#include <hip/hip_runtime.h>
#include <float.h>

#define N_TOK 32768
#define N_E   8192
#define EDIM  256
#define MU_W  0.25f

#define BM 128
#define BN 128
#define BK 32
#define NSPLIT 4
#define NRANGE (N_E / NSPLIT)   /* 2048 */
#define NTILES (NRANGE / BN)    /* 16 */

// ---------------- row squared-norm: one wave per row ----------------
__global__ __launch_bounds__(256) void rownorm_kernel(const float* __restrict__ src,
                                                      float* __restrict__ dst, int nrows) {
  int wave = threadIdx.x >> 6;
  int lane = threadIdx.x & 63;
  int row = blockIdx.x * 4 + wave;
  if (row >= nrows) return;
  const float4 v = *(const float4*)(src + (size_t)row * EDIM + lane * 4);
  float s = (v.x * v.x + v.y * v.y) + (v.z * v.z + v.w * v.w);
#pragma unroll
  for (int off = 32; off >= 1; off >>= 1) s += __shfl_xor(s, off);
  if (lane == 0) dst[row] = s;
}

// ---------------- main: fused fp32 GEMM + running argmin ----------------
// grid: (N_TOK/BM, NSPLIT); block: 256 threads (16 rg x 16 cg), 8x8 tile/thread.
__global__ __launch_bounds__(256) void vq_main_kernel(
    const float* __restrict__ x, const float* __restrict__ emb,
    const float* __restrict__ sx, const float* __restrict__ se,
    float* __restrict__ cand_d, int* __restrict__ cand_j)
{
  __shared__ float As[BK][BM + 4];   // [k][m], stride 132 floats (16B-aligned rows)
  __shared__ float Bs[BK][BN + 4];   // [k][n]

  const int tid = threadIdx.x;
  const int bm = blockIdx.x * BM;
  const int nbase = blockIdx.y * NRANGE;
  const int rg = tid >> 4;   // 0..15 row group
  const int cg = tid & 15;   // 0..15 col group

  float sxr[8];
#pragma unroll
  for (int i = 0; i < 8; ++i) {
    int row = (i < 4) ? (4 * rg + i) : (64 + 4 * rg + (i - 4));
    sxr[i] = sx[bm + row];
  }

  float dmin[8];
  int   jmin[8];
#pragma unroll
  for (int i = 0; i < 8; ++i) { dmin[i] = FLT_MAX; jmin[i] = 0; }

  const int lrow = tid >> 1;        // 0..127
  const int lks  = (tid & 1) << 4;  // 0 or 16

  for (int t = 0; t < NTILES; ++t) {
    const int n0 = nbase + t * BN;

    float acc[8][8];
#pragma unroll
    for (int i = 0; i < 8; ++i)
#pragma unroll
      for (int j = 0; j < 8; ++j) acc[i][j] = 0.f;

    for (int kc = 0; kc < EDIM; kc += BK) {
      __syncthreads();
      {
        const float* ap = x   + (size_t)(bm + lrow) * EDIM + kc + lks;
        const float* bp = emb + (size_t)(n0 + lrow) * EDIM + kc + lks;
#pragma unroll
        for (int q = 0; q < 4; ++q) {
          float4 va = *(const float4*)(ap + 4 * q);
          As[lks + 4 * q + 0][lrow] = va.x;
          As[lks + 4 * q + 1][lrow] = va.y;
          As[lks + 4 * q + 2][lrow] = va.z;
          As[lks + 4 * q + 3][lrow] = va.w;
          float4 vb = *(const float4*)(bp + 4 * q);
          Bs[lks + 4 * q + 0][lrow] = vb.x;
          Bs[lks + 4 * q + 1][lrow] = vb.y;
          Bs[lks + 4 * q + 2][lrow] = vb.z;
          Bs[lks + 4 * q + 3][lrow] = vb.w;
        }
      }
      __syncthreads();

#pragma unroll 8
      for (int kk = 0; kk < BK; ++kk) {
        float4 alo = *(const float4*)&As[kk][4 * rg];
        float4 ahi = *(const float4*)&As[kk][64 + 4 * rg];
        float4 blo = *(const float4*)&Bs[kk][4 * cg];
        float4 bhi = *(const float4*)&Bs[kk][64 + 4 * cg];
        float a[8] = {alo.x, alo.y, alo.z, alo.w, ahi.x, ahi.y, ahi.z, ahi.w};
        float b[8] = {blo.x, blo.y, blo.z, blo.w, bhi.x, bhi.y, bhi.z, bhi.w};
#pragma unroll
        for (int i = 0; i < 8; ++i)
#pragma unroll
          for (int j = 0; j < 8; ++j)
            acc[i][j] = fmaf(a[i], b[j], acc[i][j]);
      }
    }

    // epilogue: d = fl(fl(sx+se) - 2*dot), running argmin (j ascending in-thread)
    float sev[8];
#pragma unroll
    for (int j = 0; j < 8; ++j) {
      int col = (j < 4) ? (4 * cg + j) : (64 + 4 * cg + (j - 4));
      sev[j] = se[n0 + col];
    }
#pragma unroll
    for (int i = 0; i < 8; ++i) {
#pragma unroll
      for (int j = 0; j < 8; ++j) {
        int col = (j < 4) ? (4 * cg + j) : (64 + 4 * cg + (j - 4));
        float d = (sxr[i] + sev[j]) - 2.f * acc[i][j];
        int jj = n0 + col;
        if (d < dmin[i] || (d == dmin[i] && jj < jmin[i])) { dmin[i] = d; jmin[i] = jj; }
      }
    }
  }

  // reduce across the 16 cg lanes sharing each row (contiguous 16-lane groups)
#pragma unroll
  for (int off = 8; off >= 1; off >>= 1) {
#pragma unroll
    for (int i = 0; i < 8; ++i) {
      float d2 = __shfl_down(dmin[i], off, 16);
      int   j2 = __shfl_down(jmin[i], off, 16);
      if (d2 < dmin[i] || (d2 == dmin[i] && j2 < jmin[i])) { dmin[i] = d2; jmin[i] = j2; }
    }
  }
  if (cg == 0) {
#pragma unroll
    for (int i = 0; i < 8; ++i) {
      int row = (i < 4) ? (4 * rg + i) : (64 + 4 * rg + (i - 4));
      cand_d[blockIdx.y * N_TOK + bm + row] = dmin[i];
      cand_j[blockIdx.y * N_TOK + bm + row] = jmin[i];
    }
  }
}

// ---------------- gather + straight-through out + per-token loss partial ----------------
__global__ __launch_bounds__(256) void vq_gather_kernel(
    const float* __restrict__ x, const float* __restrict__ emb,
    const float* __restrict__ cand_d, const int* __restrict__ cand_j,
    float* __restrict__ out_q, float* __restrict__ out_idx,
    float* __restrict__ partials)
{
  const int token = blockIdx.x;
  const int tid = threadIdx.x;
  __shared__ int s_j;
  __shared__ float red[4];
  if (tid == 0) {
    float bd = cand_d[token];
    int   bj = cand_j[token];
#pragma unroll
    for (int s = 1; s < NSPLIT; ++s) {
      float d2 = cand_d[(size_t)s * N_TOK + token];
      int   j2 = cand_j[(size_t)s * N_TOK + token];
      if (d2 < bd || (d2 == bd && j2 < bj)) { bd = d2; bj = j2; }
    }
    s_j = bj;
    out_idx[token] = (float)bj;
  }
  __syncthreads();
  const int j = s_j;
  float xv = x[(size_t)token * EDIM + tid];
  float q  = emb[(size_t)j * EDIM + tid];
  float diff = q - xv;                       // fl(x_q - x), as reference
  out_q[(size_t)token * EDIM + tid] = xv + diff;  // x + fl(x_q - x), as reference
  float sq = diff * diff;
#pragma unroll
  for (int off = 32; off >= 1; off >>= 1) sq += __shfl_xor(sq, off);
  const int wave = tid >> 6, lane = tid & 63;
  if (lane == 0) red[wave] = sq;
  __syncthreads();
  if (tid == 0) partials[token] = (red[0] + red[1]) + (red[2] + red[3]);
}

// ---------------- final loss reduction (deterministic) ----------------
__global__ __launch_bounds__(256) void vq_loss_kernel(const float* __restrict__ partials,
                                                      float* __restrict__ loss_out)
{
  const int tid = threadIdx.x;
  float s = 0.f;
  for (int i = tid; i < N_TOK; i += 256) s += partials[i];
  __shared__ float red[4];
#pragma unroll
  for (int off = 32; off >= 1; off >>= 1) s += __shfl_xor(s, off);
  const int wave = tid >> 6, lane = tid & 63;
  if (lane == 0) red[wave] = s;
  __syncthreads();
  if (tid == 0) {
    float tot = (red[0] + red[1]) + (red[2] + red[3]);
    float mean = tot / (float)(N_TOK * EDIM);
    loss_out[0] = mean + MU_W * mean;   // codebook + MU*commitment (equal values)
  }
}

extern "C" void kernel_launch(void* const* d_in, const int* in_sizes, int n_in,
                              void* d_out, int out_size, void* d_ws, size_t ws_size,
                              hipStream_t stream) {
  const float* x   = (const float*)d_in[0];
  const float* emb = (const float*)d_in[1];

  float* out      = (float*)d_out;
  float* out_q    = out;                              // 32768*256
  float* out_loss = out + (size_t)N_TOK * EDIM;       // 1
  float* out_idx  = out_loss + 1;                     // 32768 (indices as float)

  float* cand_d   = (float*)d_ws;                     // NSPLIT*N_TOK
  int*   cand_j   = (int*)(cand_d + NSPLIT * N_TOK);  // NSPLIT*N_TOK
  float* sx       = (float*)(cand_j + NSPLIT * N_TOK);// N_TOK
  float* se       = sx + N_TOK;                       // N_E
  float* partials = se + N_E;                         // N_TOK

  rownorm_kernel<<<N_TOK / 4, 256, 0, stream>>>(x, sx, N_TOK);
  rownorm_kernel<<<N_E / 4, 256, 0, stream>>>(emb, se, N_E);

  dim3 grid(N_TOK / BM, NSPLIT);
  vq_main_kernel<<<grid, 256, 0, stream>>>(x, emb, sx, se, cand_d, cand_j);

  vq_gather_kernel<<<N_TOK, 256, 0, stream>>>(x, emb, cand_d, cand_j, out_q, out_idx, partials);
  vq_loss_kernel<<<1, 256, 0, stream>>>(partials, out_loss);
}

// Round 5
// 330.776 us; speedup vs baseline: 5.0550x; 5.0550x over previous
//
#include <hip/hip_runtime.h>
#include <float.h>
#include <stdint.h>

#define N_TOK 32768
#define N_E   8192
#define EDIM  256
#define MU_W  0.25f
#define NSPLIT 4
#define NRANGE 2048
#define BM 128
#define NTILES 16
#define MARGIN_F 2048.0f      /* scaled units (2^25): 6.1e-5 in d-units >= ref-ulp + 8-sigma noise + quant slop */
#define XSCALE 512.0f         /* 2^9 */
#define ESCALE -131072.0f     /* -2^17 ; product sums to -dot*2^26 = -2dot*2^25 */

typedef _Float16 f16;
typedef _Float16 f16x8 __attribute__((ext_vector_type(8)));
typedef _Float16 f16x4 __attribute__((ext_vector_type(4)));
typedef float f32x4 __attribute__((ext_vector_type(4)));
typedef unsigned int u32;

// ws layout (bytes)
#define WS_EMB16   0
#define WS_SX      4194304
#define WS_SE      4325376
#define WS_SE25    4358144
#define WS_CAND    4390912
#define WS_PART    6488064
#define WS_RCNT    6619136
#define WS_RLIST   6619392
#define WS_X16     6750464
#define WS_NEED_FULL 23527680ull

__device__ inline void gload_lds16(const void* g, void* l) {
  __builtin_amdgcn_global_load_lds(
      (const __attribute__((address_space(1))) unsigned int*)g,
      (__attribute__((address_space(3))) unsigned int*)l, 16, 0, 0);
}

__device__ inline u32 umin_(u32 a, u32 b) { return a < b ? a : b; }
__device__ inline u32 umax_(u32 a, u32 b) { return a > b ? a : b; }

// sorted top-4 insert (ascending u32; smaller = better)
__device__ inline void ins4(u32 v, u32& a, u32& b, u32& c, u32& d) {
  u32 mn = umin_(v, a), mx = umax_(v, a);  a = mn;
  u32 mn2 = umin_(mx, b), mx2 = umax_(mx, b); b = mn2;
  u32 mn3 = umin_(mx2, c), mx3 = umax_(mx2, c); c = mn3;
  d = umin_(mx3, d);
}

// order-preserving float->u32 map (all signs): ascending float <-> ascending u32
__device__ inline u32 fmap(float f) {
  u32 b = __float_as_uint(f);
  u32 m = (u32)((int)b >> 31) | 0x80000000u;
  return b ^ m;
}
// inverse (id bits in low 11 are noise; covered by margin slop)
__device__ inline float funmap(u32 u) {
  u32 b = (u & 0x80000000u) ? (u ^ 0x80000000u) : ~u;
  return __uint_as_float(b);
}

__global__ void zero_kernel(u32* p) { p[0] = 0u; }

// ---------------- prepass: exact rownorm tree + scaled/swizzled f16 (+ se*2^25) ----------------
__global__ __launch_bounds__(256) void conv_kernel(const float* __restrict__ src,
                                                   char* __restrict__ dst16,
                                                   float* __restrict__ norms,
                                                   float* __restrict__ norms25,
                                                   float scale, int write16, int nrows) {
  int wave = threadIdx.x >> 6;
  int lane = threadIdx.x & 63;
  int row = blockIdx.x * 4 + wave;
  if (row >= nrows) return;
  const float4 v = *(const float4*)(src + (size_t)row * EDIM + lane * 4);
  float s = (v.x * v.x + v.y * v.y) + (v.z * v.z + v.w * v.w);
#pragma unroll
  for (int off = 32; off >= 1; off >>= 1) s += __shfl_xor(s, off);
  if (lane == 0) {
    norms[row] = s;
    if (norms25) norms25[row] = s * 0x1p25f;   // exact pow2 scale of fl(se)
  }
  if (write16) {
    f16x4 h;
    h[0] = (f16)(v.x * scale); h[1] = (f16)(v.y * scale);
    h[2] = (f16)(v.z * scale); h[3] = (f16)(v.w * scale);
    int sw = (row & 7) << 4;
    *(f16x4*)(dst16 + (size_t)row * 512 + ((lane * 8) ^ sw)) = h;
  }
}

// ---------------- stage-1: fp16 MFMA GEMM (score = (se-2dot)*2^25) + packed top-4/split ----------------
template<bool XF16>
__global__ __launch_bounds__(256, 2) void vq_main(const float* __restrict__ xf,
                                                  const char* __restrict__ x16,
                                                  const char* __restrict__ e16,
                                                  const float* __restrict__ se25,
                                                  u32* __restrict__ cand) {
  __shared__ f16 Abuf[128 * 128];            // 32 KB swizzled half-K panel
  __shared__ f16 Bbuf[128 * 128];            // 32 KB
  __shared__ u32 scratch[4][4][16][4];       // 4 KB inter-wave merge

  const int tid = threadIdx.x;
  const int lane = tid & 63;
  const int wid = tid >> 6;
  const int wm = wid >> 1, wn = wid & 1;
  const int l15 = lane & 15;
  const int lg = lane >> 4;
  const int split = blockIdx.x & 3;
  const int bm = (blockIdx.x >> 2) * BM;
  const int nbase = split * NRANGE;

  u32 d1[16], d2[16], d3[16], d4[16];
#pragma unroll
  for (int s = 0; s < 16; ++s) { d1[s] = 0xFFFFFFFFu; d2[s] = 0xFFFFFFFFu; d3[s] = 0xFFFFFFFFu; d4[s] = 0xFFFFFFFFu; }

  for (int t = 0; t < NTILES; ++t) {
    const int n0 = nbase + t * 128;

    float sev[4];
#pragma unroll
    for (int ni = 0; ni < 4; ++ni) sev[ni] = se25[n0 + wn * 64 + ni * 16 + l15];

    f32x4 acc[4][4];
#pragma unroll
    for (int mi = 0; mi < 4; ++mi)
#pragma unroll
      for (int ni = 0; ni < 4; ++ni)
        acc[mi][ni] = (f32x4){sev[ni], sev[ni], sev[ni], sev[ni]};

#pragma unroll
    for (int h = 0; h < 2; ++h) {
      __syncthreads();
      {
        const char* bbase = e16 + (size_t)(nbase + t * 128) * 512 + h * 256;
#pragma unroll
        for (int it = 0; it < 8; ++it) {
          int c = wid * 8 + it;
          int Lrel = c * 1024 + lane * 16;
          int col = Lrel >> 8, p = Lrel & 255;
          gload_lds16(bbase + col * 512 + p, (char*)Bbuf + c * 1024);
        }
      }
      if (XF16) {
        const char* abase = x16 + (size_t)bm * 512 + h * 256;
#pragma unroll
        for (int it = 0; it < 8; ++it) {
          int c = wid * 8 + it;
          int Lrel = c * 1024 + lane * 16;
          int col = Lrel >> 8, p = Lrel & 255;
          gload_lds16(abase + col * 512 + p, (char*)Abuf + c * 1024);
        }
      } else {
        int row = tid >> 1, sub = tid & 1;
        const float4* xs = (const float4*)xf + (size_t)(bm + row) * 64 + h * 32 + sub * 16;
        char* ab = (char*)Abuf + row * 256;
        int sw = (row & 7) << 4;
#pragma unroll
        for (int q = 0; q < 8; ++q) {
          float4 a0 = xs[q * 2], a1 = xs[q * 2 + 1];
          f16x8 hv;
          hv[0] = (f16)(a0.x * XSCALE); hv[1] = (f16)(a0.y * XSCALE);
          hv[2] = (f16)(a0.z * XSCALE); hv[3] = (f16)(a0.w * XSCALE);
          hv[4] = (f16)(a1.x * XSCALE); hv[5] = (f16)(a1.y * XSCALE);
          hv[6] = (f16)(a1.z * XSCALE); hv[7] = (f16)(a1.w * XSCALE);
          *(f16x8*)(ab + ((sub * 128 + q * 16) ^ sw)) = hv;
        }
      }
      __syncthreads();

#pragma unroll
      for (int kk = 0; kk < 4; ++kk) {
        f16x8 av[4], bv[4];
#pragma unroll
        for (int mi = 0; mi < 4; ++mi) {
          int ar = wm * 64 + mi * 16 + l15;
          av[mi] = *(const f16x8*)((const char*)Abuf + ar * 256 +
                                   ((kk * 64 + lg * 16) ^ ((ar & 7) << 4)));
        }
#pragma unroll
        for (int ni = 0; ni < 4; ++ni) {
          int br = wn * 64 + ni * 16 + l15;
          bv[ni] = *(const f16x8*)((const char*)Bbuf + br * 256 +
                                   ((kk * 64 + lg * 16) ^ ((br & 7) << 4)));
        }
#pragma unroll
        for (int mi = 0; mi < 4; ++mi)
#pragma unroll
          for (int ni = 0; ni < 4; ++ni)
            acc[mi][ni] = __builtin_amdgcn_mfma_f32_16x16x32_f16(av[mi], bv[ni], acc[mi][ni], 0, 0, 0);
      }
    }

    // ---- epilogue: sign-neutral monotone pack (low 11 bits = candidate id) + top-4 ----
#pragma unroll
    for (int ni = 0; ni < 4; ++ni) {
      u32 id = (u32)((t << 7) | (wn << 6) | (ni << 4) | l15);
#pragma unroll
      for (int mi = 0; mi < 4; ++mi)
#pragma unroll
        for (int r = 0; r < 4; ++r) {
          u32 up = (fmap(acc[mi][ni][r]) & 0xFFFFF800u) | id;
          int s = mi * 4 + r;
          ins4(up, d1[s], d2[s], d3[s], d4[s]);
        }
    }
  }

  // ---- intra-group (16-lane) butterfly merge ----
#pragma unroll
  for (int off = 8; off >= 1; off >>= 1) {
#pragma unroll
    for (int s = 0; s < 16; ++s) {
      u32 e1 = (u32)__shfl_xor((int)d1[s], off);
      u32 e2 = (u32)__shfl_xor((int)d2[s], off);
      u32 e3 = (u32)__shfl_xor((int)d3[s], off);
      u32 e4 = (u32)__shfl_xor((int)d4[s], off);
      ins4(e1, d1[s], d2[s], d3[s], d4[s]);
      ins4(e2, d1[s], d2[s], d3[s], d4[s]);
      ins4(e3, d1[s], d2[s], d3[s], d4[s]);
      ins4(e4, d1[s], d2[s], d3[s], d4[s]);
    }
  }
  if (l15 == 0) {
#pragma unroll
    for (int s = 0; s < 16; ++s) {
      scratch[wid][lg][s][0] = d1[s];
      scratch[wid][lg][s][1] = d2[s];
      scratch[wid][lg][s][2] = d3[s];
      scratch[wid][lg][s][3] = d4[s];
    }
  }
  __syncthreads();
  if (tid < 128) {
    int row = tid;
    int wmr = row >> 6, mi = (row >> 4) & 3, lgr = (row >> 2) & 3, rr = row & 3;
    int s = mi * 4 + rr;
    u32 a1 = scratch[wmr * 2 + 0][lgr][s][0];
    u32 a2 = scratch[wmr * 2 + 0][lgr][s][1];
    u32 a3 = scratch[wmr * 2 + 0][lgr][s][2];
    u32 a4 = scratch[wmr * 2 + 0][lgr][s][3];
    ins4(scratch[wmr * 2 + 1][lgr][s][0], a1, a2, a3, a4);
    ins4(scratch[wmr * 2 + 1][lgr][s][1], a1, a2, a3, a4);
    ins4(scratch[wmr * 2 + 1][lgr][s][2], a1, a2, a3, a4);
    ins4(scratch[wmr * 2 + 1][lgr][s][3], a1, a2, a3, a4);
    size_t base = (size_t)split * (N_TOK * 4) + (size_t)(bm + row) * 4;
    cand[base + 0] = a1; cand[base + 1] = a2; cand[base + 2] = a3; cand[base + 3] = a4;
  }
}

// ---------------- gather: float-margin select + guard + exact refine + output ----------------
__global__ __launch_bounds__(256) void vq_gather_kernel(
    const float* __restrict__ x, const float* __restrict__ emb,
    const float* __restrict__ sx, const float* __restrict__ se,
    const u32* __restrict__ cand,
    float* __restrict__ out_q, float* __restrict__ out_idx,
    float* __restrict__ partials,
    u32* __restrict__ rcnt, u32* __restrict__ rlist) {
  const int token = blockIdx.x;
  const int tid = threadIdx.x;
  __shared__ int s_j;
  __shared__ int s_cnt;
  __shared__ int s_cj[16];
  __shared__ float s_dv[16];
  __shared__ float red[4];

  if (tid == 0) {
    u32 u[16];
    float uf[16];
    float gmin = FLT_MAX;
#pragma unroll
    for (int sp = 0; sp < 4; ++sp)
#pragma unroll
      for (int c = 0; c < 4; ++c) {
        u32 v = cand[(size_t)sp * (N_TOK * 4) + (size_t)token * 4 + c];
        u[sp * 4 + c] = v;
        float f = funmap(v);
        uf[sp * 4 + c] = f;
        gmin = fminf(gmin, f);
      }
    // guard: if any split's 4th-best is within margin of global best, top-4
    // cannot prove it holds all within-margin candidates -> exact full rescan
    bool guard = false;
#pragma unroll
    for (int sp = 0; sp < 4; ++sp) guard = guard || (uf[sp * 4 + 3] <= gmin + MARGIN_F);
    int cnt;
    if (guard) {
      u32 slot = atomicAdd(rcnt, 1u);
      rlist[slot] = (u32)token;
      cnt = -1;
    } else {
      cnt = 0;
#pragma unroll
      for (int sp = 0; sp < 4; ++sp)
#pragma unroll
        for (int c = 0; c < 4; ++c) {
          int k = sp * 4 + c;
          if (uf[k] <= gmin + MARGIN_F) {
            u32 idx = u[k] & 0x7FFu;
            int col = (int)((idx >> 7) & 15) * 128 + (int)((idx >> 6) & 1) * 64 +
                      (int)((idx >> 4) & 3) * 16 + (int)(idx & 15);
            s_cj[cnt++] = sp * NRANGE + col;
          }
        }
      if (cnt == 1) s_j = s_cj[0];
    }
    s_cnt = cnt;
  }
  __syncthreads();
  int cnt = s_cnt;
  if (cnt < 0) return;   // uniform: token handled by rescan kernel
  if (cnt > 1 && tid < cnt) {
    int j = s_cj[tid];
    const float* xr = x + (size_t)token * EDIM;
    const float* er = emb + (size_t)j * EDIM;
    float a = 0.f;
    for (int k = 0; k < EDIM; ++k) a = fmaf(xr[k], er[k], a);   // round-1 exact chain
    s_dv[tid] = (sx[token] + se[j]) - 2.0f * a;                  // round-1 exact epilogue
  }
  __syncthreads();
  if (cnt > 1 && tid == 0) {
    float bd = s_dv[0]; int bj = s_cj[0];
    for (int c = 1; c < cnt; ++c) {
      float d = s_dv[c]; int j = s_cj[c];
      if (d < bd || (d == bd && j < bj)) { bd = d; bj = j; }
    }
    s_j = bj;
  }
  __syncthreads();
  const int j = s_j;
  if (tid == 0) out_idx[token] = (float)j;
  float xv = x[(size_t)token * EDIM + tid];
  float q  = emb[(size_t)j * EDIM + tid];
  float diff = q - xv;
  out_q[(size_t)token * EDIM + tid] = xv + diff;
  float sq = diff * diff;
#pragma unroll
  for (int off = 32; off >= 1; off >>= 1) sq += __shfl_xor(sq, off);
  const int wave = tid >> 6, lane = tid & 63;
  if (lane == 0) red[wave] = sq;
  __syncthreads();
  if (tid == 0) partials[token] = (red[0] + red[1]) + (red[2] + red[3]);
}

// ---------------- rescan: exact full argmin (round-1 arithmetic) for guarded tokens ----------------
__global__ __launch_bounds__(256) void vq_rescan_kernel(
    const float* __restrict__ x, const float* __restrict__ emb,
    const float* __restrict__ sx, const float* __restrict__ se,
    const u32* __restrict__ rcnt, const u32* __restrict__ rlist,
    float* __restrict__ out_q, float* __restrict__ out_idx,
    float* __restrict__ partials) {
  const int tid = threadIdx.x;
  const int n = (int)rcnt[0];
  __shared__ float xs[EDIM];
  __shared__ float rd[4];
  __shared__ int   rj[4];
  __shared__ int   s_bj;

  for (int it = blockIdx.x; it < n; it += gridDim.x) {
    const int token = (int)rlist[it];
    xs[tid] = x[(size_t)token * EDIM + tid];
    __syncthreads();
    const float sxt = sx[token];
    float bd = FLT_MAX; int bj = 0;
    for (int c = 0; c < N_E / 256; ++c) {
      int j = tid * (N_E / 256) + c;
      const float* er = emb + (size_t)j * EDIM;
      float a = 0.f;
      for (int k = 0; k < EDIM; ++k) a = fmaf(xs[k], er[k], a);  // round-1 exact chain
      float d = (sxt + se[j]) - 2.0f * a;
      if (d < bd || (d == bd && j < bj)) { bd = d; bj = j; }
    }
    const int lane = tid & 63, wave = tid >> 6;
#pragma unroll
    for (int off = 32; off >= 1; off >>= 1) {
      float d2 = __shfl_xor(bd, off);
      int   j2 = __shfl_xor(bj, off);
      if (d2 < bd || (d2 == bd && j2 < bj)) { bd = d2; bj = j2; }
    }
    if (lane == 0) { rd[wave] = bd; rj[wave] = bj; }
    __syncthreads();
    if (tid == 0) {
      float bbd = rd[0]; int bbj = rj[0];
#pragma unroll
      for (int w = 1; w < 4; ++w) {
        if (rd[w] < bbd || (rd[w] == bbd && rj[w] < bbj)) { bbd = rd[w]; bbj = rj[w]; }
      }
      s_bj = bbj;
      out_idx[token] = (float)bbj;
    }
    __syncthreads();
    const int j = s_bj;
    float xv = xs[tid];
    float q  = emb[(size_t)j * EDIM + tid];
    float diff = q - xv;
    out_q[(size_t)token * EDIM + tid] = xv + diff;
    float sq = diff * diff;
#pragma unroll
    for (int off = 32; off >= 1; off >>= 1) sq += __shfl_xor(sq, off);
    if (lane == 0) rd[wave] = sq;
    __syncthreads();
    if (tid == 0) partials[token] = (rd[0] + rd[1]) + (rd[2] + rd[3]);
    __syncthreads();
  }
}

// ---------------- final loss reduction ----------------
__global__ __launch_bounds__(256) void vq_loss_kernel(const float* __restrict__ partials,
                                                      float* __restrict__ loss_out) {
  const int tid = threadIdx.x;
  float s = 0.f;
  for (int i = tid; i < N_TOK; i += 256) s += partials[i];
  __shared__ float red[4];
#pragma unroll
  for (int off = 32; off >= 1; off >>= 1) s += __shfl_xor(s, off);
  const int wave = tid >> 6, lane = tid & 63;
  if (lane == 0) red[wave] = s;
  __syncthreads();
  if (tid == 0) {
    float tot = (red[0] + red[1]) + (red[2] + red[3]);
    float mean = tot / (float)(N_TOK * EDIM);
    loss_out[0] = mean + MU_W * mean;
  }
}

extern "C" void kernel_launch(void* const* d_in, const int* in_sizes, int n_in,
                              void* d_out, int out_size, void* d_ws, size_t ws_size,
                              hipStream_t stream) {
  const float* x   = (const float*)d_in[0];
  const float* emb = (const float*)d_in[1];

  float* out      = (float*)d_out;
  float* out_q    = out;
  float* out_loss = out + (size_t)N_TOK * EDIM;
  float* out_idx  = out_loss + 1;

  char* w = (char*)d_ws;
  char*  emb16    = w + WS_EMB16;
  float* sx       = (float*)(w + WS_SX);
  float* se       = (float*)(w + WS_SE);
  float* se25     = (float*)(w + WS_SE25);
  u32*   cand     = (u32*)(w + WS_CAND);
  float* partials = (float*)(w + WS_PART);
  u32*   rcnt     = (u32*)(w + WS_RCNT);
  u32*   rlist    = (u32*)(w + WS_RLIST);
  char*  x16      = w + WS_X16;

  const bool xf16 = (ws_size >= WS_NEED_FULL);

  zero_kernel<<<1, 1, 0, stream>>>(rcnt);
  conv_kernel<<<N_E / 4, 256, 0, stream>>>(emb, emb16, se, se25, ESCALE, 1, N_E);
  conv_kernel<<<N_TOK / 4, 256, 0, stream>>>(x, x16, sx, nullptr, XSCALE, xf16 ? 1 : 0, N_TOK);

  if (xf16)
    vq_main<true><<<NSPLIT * (N_TOK / BM), 256, 0, stream>>>(x, x16, emb16, se25, cand);
  else
    vq_main<false><<<NSPLIT * (N_TOK / BM), 256, 0, stream>>>(x, x16, emb16, se25, cand);

  vq_gather_kernel<<<N_TOK, 256, 0, stream>>>(x, emb, sx, se, cand, out_q, out_idx, partials,
                                              rcnt, rlist);
  vq_rescan_kernel<<<256, 256, 0, stream>>>(x, emb, sx, se, rcnt, rlist, out_q, out_idx, partials);
  vq_loss_kernel<<<1, 256, 0, stream>>>(partials, out_loss);
}